// Round 1
// baseline (6000.975 us; speedup 1.0000x reference)
//
#include <hip/hip_runtime.h>

#define T_STEPS 4096
#define M_BATCH 512
#define D_INP   11
#define N_HID   51
#define G4      204   // 4*N

__launch_bounds__(256, 2)
__global__ void lstm2_persistent(
    const float* __restrict__ input,   // [T, M, D_INP]
    const float* __restrict__ W_ih1,   // [204, 11]
    const float* __restrict__ W_hh1,   // [204, 51]
    const float* __restrict__ b_ih1,   // [204]
    const float* __restrict__ b_hh1,   // [204]
    const float* __restrict__ W_ih2,   // [204, 51]
    const float* __restrict__ W_hh2,   // [204, 51]
    const float* __restrict__ b_ih2,   // [204]
    const float* __restrict__ b_hh2,   // [204]
    const float* __restrict__ W_lin,   // [1, 51]
    const float* __restrict__ b_lin,   // [1]
    float* __restrict__ out)           // [M, T]
{
    const int b   = blockIdx.x;        // batch element, one block per element
    const int tid = threadIdx.x;
    const int j   = (tid < G4) ? tid : (G4 - 1);   // gate owned by this thread

    __shared__ float sh_h1[64];
    __shared__ float sh_h2[64];
    __shared__ float sh_act1[256];
    __shared__ float sh_act2[256];

    // ---- persistent register-resident weights for gate j ----
    float wi1[D_INP], wh1[N_HID], wi2[N_HID], wh2[N_HID];
    #pragma unroll
    for (int k = 0; k < D_INP; ++k) wi1[k] = W_ih1[j * D_INP + k];
    #pragma unroll
    for (int k = 0; k < N_HID; ++k) wh1[k] = W_hh1[j * N_HID + k];
    #pragma unroll
    for (int k = 0; k < N_HID; ++k) wi2[k] = W_ih2[j * N_HID + k];
    #pragma unroll
    for (int k = 0; k < N_HID; ++k) wh2[k] = W_hh2[j * N_HID + k];
    const float bias1 = b_ih1[j] + b_hh1[j];
    const float bias2 = b_ih2[j] + b_hh2[j];

    // activation as act = Aa * sigmoid(Sa*x) + Ba  (tanh(x) = 2*sigmoid(2x)-1)
    const bool  is_g = (j >= 2 * N_HID) && (j < 3 * N_HID);
    const float Sa = is_g ? 2.0f : 1.0f;
    const float Aa = is_g ? 2.0f : 1.0f;
    const float Ba = is_g ? -1.0f : 0.0f;

    const float wlin = (tid < N_HID) ? W_lin[tid] : 0.0f;
    const float blin = b_lin[0];

    float c1 = 0.0f, c2 = 0.0f;
    if (tid < 64) { sh_h1[tid] = 0.0f; sh_h2[tid] = 0.0f; }
    __syncthreads();

    float*       outp = out + (size_t)b * T_STEPS;
    const float* xrow = input + (size_t)b * D_INP;

    // software-pipelined x fetch (block-uniform address -> scalar loads)
    float xv[D_INP];
    #pragma unroll
    for (int k = 0; k < D_INP; ++k) xv[k] = xrow[k];

    for (int t = 0; t < T_STEPS; ++t) {
        // prefetch x for t+1 (clamped) — consumed next iteration
        const float* xnext = xrow + (size_t)((t + 1 < T_STEPS) ? t + 1 : t) * (M_BATCH * D_INP);
        float xn[D_INP];
        #pragma unroll
        for (int k = 0; k < D_INP; ++k) xn[k] = xnext[k];

        // ---- layer 1 gates: dot(x, Wih1[j]) + dot(h1, Whh1[j]) + bias ----
        float acc = bias1;
        #pragma unroll
        for (int k = 0; k < D_INP; ++k) acc += xv[k] * wi1[k];
        #pragma unroll
        for (int k = 0; k < N_HID; ++k) acc += sh_h1[k] * wh1[k];
        float e1 = __expf(-Sa * acc);
        sh_act1[tid] = Aa * __builtin_amdgcn_rcpf(1.0f + e1) + Ba;
        __syncthreads();

        // ---- layer 1 state update (threads 0..50 own h/c element tid) ----
        if (tid < N_HID) {
            float ig = sh_act1[tid];
            float fg = sh_act1[N_HID + tid];
            float gg = sh_act1[2 * N_HID + tid];
            float og = sh_act1[3 * N_HID + tid];
            c1 = fg * c1 + ig * gg;
            float et = __expf(-2.0f * c1);
            float th = 2.0f * __builtin_amdgcn_rcpf(1.0f + et) - 1.0f;
            sh_h1[tid] = og * th;
        }
        __syncthreads();

        // ---- layer 2 gates: dot(h1, Wih2[j]) + dot(h2, Whh2[j]) + bias ----
        float acc2 = bias2;
        #pragma unroll
        for (int k = 0; k < N_HID; ++k) acc2 += sh_h1[k] * wi2[k];
        #pragma unroll
        for (int k = 0; k < N_HID; ++k) acc2 += sh_h2[k] * wh2[k];
        float e2 = __expf(-Sa * acc2);
        sh_act2[tid] = Aa * __builtin_amdgcn_rcpf(1.0f + e2) + Ba;
        __syncthreads();

        // ---- layer 2 update + projection ----
        float part = 0.0f;
        if (tid < N_HID) {
            float ig = sh_act2[tid];
            float fg = sh_act2[N_HID + tid];
            float gg = sh_act2[2 * N_HID + tid];
            float og = sh_act2[3 * N_HID + tid];
            c2 = fg * c2 + ig * gg;
            float et = __expf(-2.0f * c2);
            float th = 2.0f * __builtin_amdgcn_rcpf(1.0f + et) - 1.0f;
            float h2v = og * th;
            sh_h2[tid] = h2v;
            part = h2v * wlin;
        }
        if (tid < 64) {
            #pragma unroll
            for (int off = 32; off > 0; off >>= 1)
                part += __shfl_down(part, off, 64);
            if (tid == 0) outp[t] = part + blin;
        }
        // no barrier needed here: next read of sh_h2 (layer-2 dot) is after
        // next iteration's second barrier; sh_h1 reads are covered likewise.

        #pragma unroll
        for (int k = 0; k < D_INP; ++k) xv[k] = xn[k];
    }
}

extern "C" void kernel_launch(void* const* d_in, const int* in_sizes, int n_in,
                              void* d_out, int out_size, void* d_ws, size_t ws_size,
                              hipStream_t stream) {
    const float* input = (const float*)d_in[0];
    const float* W_ih1 = (const float*)d_in[1];
    const float* W_hh1 = (const float*)d_in[2];
    const float* b_ih1 = (const float*)d_in[3];
    const float* b_hh1 = (const float*)d_in[4];
    const float* W_ih2 = (const float*)d_in[5];
    const float* W_hh2 = (const float*)d_in[6];
    const float* b_ih2 = (const float*)d_in[7];
    const float* b_hh2 = (const float*)d_in[8];
    const float* W_lin = (const float*)d_in[9];
    const float* b_lin = (const float*)d_in[10];
    float* out = (float*)d_out;

    lstm2_persistent<<<M_BATCH, 256, 0, stream>>>(
        input, W_ih1, W_hh1, b_ih1, b_hh1,
        W_ih2, W_hh2, b_ih2, b_hh2, W_lin, b_lin, out);
}

// Round 2
// 5202.071 us; speedup vs baseline: 1.1536x; 1.1536x over previous
//
#include <hip/hip_runtime.h>

#define T_STEPS 4096
#define M_BATCH 512
#define D_INP   11
#define N_HID   51
#define G4      204   // 4*N

typedef float v4f __attribute__((ext_vector_type(4)));

#define PIN4(v) asm volatile("" : "+v"(v))

__attribute__((amdgpu_waves_per_eu(2, 2)))
__launch_bounds__(256)
__global__ void lstm2_persistent(
    const float* __restrict__ input,   // [T, M, D_INP]
    const float* __restrict__ W_ih1,   // [204, 11]
    const float* __restrict__ W_hh1,   // [204, 51]
    const float* __restrict__ b_ih1,   // [204]
    const float* __restrict__ b_hh1,   // [204]
    const float* __restrict__ W_ih2,   // [204, 51]
    const float* __restrict__ W_hh2,   // [204, 51]
    const float* __restrict__ b_ih2,   // [204]
    const float* __restrict__ b_hh2,   // [204]
    const float* __restrict__ W_lin,   // [1, 51]
    const float* __restrict__ b_lin,   // [1]
    float* __restrict__ out)           // [M, T]
{
    const int b   = blockIdx.x;
    const int tid = threadIdx.x;
    const int j   = (tid < G4) ? tid : (G4 - 1);

    // LDS: h-state (h1: floats 0..51, h2: 52..103, pads at 51/103 stay 0),
    // double-buffered x (12 floats per slot, pad at [11]/[23] stays 0),
    // gate activations.
    __shared__ __align__(16) float sh_state[104];
    __shared__ __align__(16) float sh_x[24];
    __shared__ float sh_act1[256];
    __shared__ float sh_act2[256];

    // ---- register-resident weights, packed for v_pk_fma_f32 ----
    v4f wi1[3], wh1[13], wi2[13], wh2[13];
    #pragma unroll
    for (int k4 = 0; k4 < 3; ++k4)
        #pragma unroll
        for (int e = 0; e < 4; ++e) {
            int k = k4 * 4 + e;
            wi1[k4][e] = (k < D_INP) ? W_ih1[j * D_INP + k] : 0.0f;
        }
    #pragma unroll
    for (int k4 = 0; k4 < 13; ++k4)
        #pragma unroll
        for (int e = 0; e < 4; ++e) {
            int k = k4 * 4 + e;
            wh1[k4][e] = (k < N_HID) ? W_hh1[j * N_HID + k] : 0.0f;
            wi2[k4][e] = (k < N_HID) ? W_ih2[j * N_HID + k] : 0.0f;
            wh2[k4][e] = (k < N_HID) ? W_hh2[j * N_HID + k] : 0.0f;
        }
    const float bias1 = b_ih1[j] + b_hh1[j];
    const float bias2 = b_ih2[j] + b_hh2[j];

    // act = Aa * sigmoid(Sa*x) + Ba  (tanh(x) = 2*sigmoid(2x)-1 for g-gate)
    const bool  is_g = (j >= 2 * N_HID) && (j < 3 * N_HID);
    const float Sa = is_g ? 2.0f : 1.0f;
    const float Aa = is_g ? 2.0f : 1.0f;
    const float Ba = is_g ? -1.0f : 0.0f;

    const float wlin = (tid < N_HID) ? W_lin[tid] : 0.0f;
    const float blin = b_lin[0];

    float c1 = 0.0f, c2 = 0.0f;

    if (tid < 104) sh_state[tid] = 0.0f;
    if (tid < 24)  sh_x[tid] = 0.0f;
    if (tid < D_INP) sh_x[tid] = input[(size_t)b * D_INP + tid];  // x(0) into slot 0
    __syncthreads();

    float* outp = out + (size_t)b * T_STEPS;
    const v4f* hv = (const v4f*)sh_state;   // h1: [0..12], h2: [13..25]

    for (int t = 0; t < T_STEPS; ++t) {
        // keep weights live in VGPRs across the whole loop body
        #pragma unroll
        for (int k4 = 0; k4 < 3; ++k4) PIN4(wi1[k4]);
        #pragma unroll
        for (int k4 = 0; k4 < 13; ++k4) { PIN4(wh1[k4]); PIN4(wi2[k4]); PIN4(wh2[k4]); }

        // prefetch x(t+1) early (global, block-uniform row; 11 lanes)
        float xg = 0.0f;
        const int tn = (t + 1 < T_STEPS) ? t + 1 : t;
        if (tid < D_INP)
            xg = input[(size_t)tn * (M_BATCH * D_INP) + (size_t)b * D_INP + tid];

        // ---- phase 1: layer-1 gates ----
        const v4f* xs = (const v4f*)(sh_x + (t & 1) * 12);
        v4f a0 = {0.f, 0.f, 0.f, 0.f}, a1 = {0.f, 0.f, 0.f, 0.f};
        a0 += xs[0] * wi1[0];
        a1 += xs[1] * wi1[1];
        a0 += xs[2] * wi1[2];
        #pragma unroll
        for (int k4 = 0; k4 < 13; ++k4) {
            if (k4 & 1) a1 += hv[k4] * wh1[k4];
            else        a0 += hv[k4] * wh1[k4];
        }
        v4f asum = a0 + a1;
        float g1 = (asum.x + asum.y) + (asum.z + asum.w) + bias1;
        float e1 = __expf(-Sa * g1);
        sh_act1[tid] = Aa * __builtin_amdgcn_rcpf(1.0f + e1) + Ba;
        __syncthreads();                                   // B1

        // ---- phase 2: layer-1 state update (lanes 0..50 of wave 0) ----
        if (tid < N_HID) {
            float ig = sh_act1[tid];
            float fg = sh_act1[N_HID + tid];
            float gg = sh_act1[2 * N_HID + tid];
            float og = sh_act1[3 * N_HID + tid];
            c1 = fg * c1 + ig * gg;
            float et = __expf(-2.0f * c1);
            float th = 2.0f * __builtin_amdgcn_rcpf(1.0f + et) - 1.0f;
            sh_state[tid] = og * th;                       // h1
        }
        __syncthreads();                                   // B2

        // ---- phase 3: layer-2 gates ----
        v4f b0 = {0.f, 0.f, 0.f, 0.f}, b1v = {0.f, 0.f, 0.f, 0.f};
        #pragma unroll
        for (int k4 = 0; k4 < 13; ++k4) {
            if (k4 & 1) b1v += hv[k4] * wi2[k4];
            else        b0  += hv[k4] * wi2[k4];
        }
        #pragma unroll
        for (int k4 = 0; k4 < 13; ++k4) {
            if (k4 & 1) b1v += hv[13 + k4] * wh2[k4];
            else        b0  += hv[13 + k4] * wh2[k4];
        }
        v4f bsum = b0 + b1v;
        float g2 = (bsum.x + bsum.y) + (bsum.z + bsum.w) + bias2;
        float e2 = __expf(-Sa * g2);
        sh_act2[tid] = Aa * __builtin_amdgcn_rcpf(1.0f + e2) + Ba;
        // stash prefetched x(t+1) into the other LDS slot (covered by B3)
        if (tid < D_INP) sh_x[((t + 1) & 1) * 12 + tid] = xg;
        __syncthreads();                                   // B3

        // ---- phase 4: layer-2 state update + projection ----
        float part = 0.0f;
        if (tid < N_HID) {
            float ig = sh_act2[tid];
            float fg = sh_act2[N_HID + tid];
            float gg = sh_act2[2 * N_HID + tid];
            float og = sh_act2[3 * N_HID + tid];
            c2 = fg * c2 + ig * gg;
            float et = __expf(-2.0f * c2);
            float th = 2.0f * __builtin_amdgcn_rcpf(1.0f + et) - 1.0f;
            float h2v = og * th;
            sh_state[52 + tid] = h2v;                      // h2
            part = h2v * wlin;
        }
        if (tid < 64) {
            #pragma unroll
            for (int off = 32; off > 0; off >>= 1)
                part += __shfl_down(part, off, 64);
            if (tid == 0) outp[t] = part + blin;
        }
        // no barrier here: sh_h2 written now is first read in phase 3 of
        // t+1 (after B1,B2); sh_act2 is next written after B1,B2 of t+1.
    }
}

extern "C" void kernel_launch(void* const* d_in, const int* in_sizes, int n_in,
                              void* d_out, int out_size, void* d_ws, size_t ws_size,
                              hipStream_t stream) {
    const float* input = (const float*)d_in[0];
    const float* W_ih1 = (const float*)d_in[1];
    const float* W_hh1 = (const float*)d_in[2];
    const float* b_ih1 = (const float*)d_in[3];
    const float* b_hh1 = (const float*)d_in[4];
    const float* W_ih2 = (const float*)d_in[5];
    const float* W_hh2 = (const float*)d_in[6];
    const float* b_ih2 = (const float*)d_in[7];
    const float* b_hh2 = (const float*)d_in[8];
    const float* W_lin = (const float*)d_in[9];
    const float* b_lin = (const float*)d_in[10];
    float* out = (float*)d_out;

    lstm2_persistent<<<M_BATCH, 256, 0, stream>>>(
        input, W_ih1, W_hh1, b_ih1, b_hh1,
        W_ih2, W_hh2, b_ih2, b_hh2, W_lin, b_lin, out);
}